// Round 7
// baseline (9.678 us; speedup 1.0000x reference)
//
#include <hip/hip_runtime.h>
#include <math.h>

// Exact algebra, two stages:
//  (1) Light-cone reduction: 24-qubit circuit -> product of 5 single-qubit
//      real density matrices on wires {2,5,10,18,21}
//      (DM bit b: 0->w2, 1->w5, 2->w10, 3->w18, 4->w21).
//  (2) Mixture-of-pure-states: 32 weighted product pure states, one branch
//      per lane-in-32; statevector bit 4 SPLIT ACROSS WAVE HALVES (round 7):
//      one node per 64-lane wave, lane = (branch, i4-half), 16 amps/lane.
//      Delayed-merge evolution + commutation moves; th50 now pre-merge on
//      q012 (commutes past cx(2->3)..cx(3->4)). b4 gates are cross-half
//      shfl_xor(32) ops. Final 5 RYs (th52-56) folded into measurement via
//      RY^T Z RY = cos Z - sin X. No LDS, no barriers.

__device__ __forceinline__ void ry_dm(float& a, float& b, float& d, float c, float s) {
    float na = c*c*a - 2.0f*c*s*b + s*s*d;
    float nb = c*s*(a - d) + (c*c - s*s)*b;
    float nd = s*s*a + 2.0f*c*s*b + c*c*d;
    a = na; b = nb; d = nd;
}

template<int MASK>
__device__ __forceinline__ void apply_ry16(float* amp, float c, float s) {
#pragma unroll
    for (int i = 0; i < 16; ++i) {
        if (!(i & MASK)) {
            float x = amp[i], y = amp[i | MASK];
            amp[i]        = c * x - s * y;
            amp[i | MASK] = s * x + c * y;
        }
    }
}

__global__ __launch_bounds__(64) void nodenet_branch_kernel(
    const float* __restrict__ X, const float* __restrict__ e,
    const float* __restrict__ Ri, const float* __restrict__ Ro,
    const float* __restrict__ th, float* __restrict__ out)
{
    const int t    = threadIdx.x;            // 0..63
    const int node = blockIdx.x;              // one node per wave
    const int lig  = t & 31;                  // branch id (same on both halves)
    const int half = t >> 5;                   // i4 value owned by this lane

    // ---- Phase A (unified + E-halved across wave halves):
    // lanes lig<16 compute angle for wire w=lig (w<8: mi, else mo), E-range
    // [8*half, 8*half+8); shfl_xor(32) combines halves.
    float Mv;
    {
        const int w    = lig;
        const int dcol = w & 7;
        const float* Aouter = ((w & 8) == 0) ? Ri : Ro;
        const float* Ainner = ((w & 8) == 0) ? Ro : Ri;
        const float x0 = X[0*8 + dcol], x1 = X[1*8 + dcol],
                    x2 = X[2*8 + dcol], x3 = X[3*8 + dcol];
        float acc = 0.0f;
        const int E0 = half * 8;
#pragma unroll
        for (int E = 0; E < 8; ++E) {
            const int Ei = E0 + E;
            float bsum = Ainner[0*16 + Ei]*x0 + Ainner[1*16 + Ei]*x1
                       + Ainner[2*16 + Ei]*x2 + Ainner[3*16 + Ei]*x3;
            acc += Aouter[node*16 + Ei] * e[Ei] * bsum;
        }
        acc += __shfl_xor(acc, 32);          // combine E-halves
        Mv = (lig < 16) ? acc : X[node*8 + ((lig - 16) & 7)];
    }

    // ---- Gate-angle sincos (half-angle), ids 0..20 on lanes 0..20 (both halves) ----
    float gs, gc;
    {
        const int id = (lig < 21) ? lig : 0;
        __sincosf(0.5f * th[36 + id], &gs, &gc);
    }

    // ---- Phase B: chains (slot ss = lane 0..5; upper half duplicates) ----
    const int ss = (lig < 6) ? lig : 0;
    const int Q   = ss==0?2 : ss==1?5 : ss==2?10 : ss==3?13 : ss==4?18 : 21;
    const int P   = ss==0?3 : ss==1?4 : ss==2?11 : ss==3?12 : ss==4?19 : 20;
    const int C   = ss==0?1 : ss==1?6 : ss==2?9  : ss==3?14 : ss==4?17 : 22;
    const int PC  = ss==0?0 : ss==1?7 : ss==2?8  : ss==3?15 : ss==4?16 : 23;
    const int tq2 = ss==0?25: ss==1?26: ss==2?29 : ss==3?30 : ss==4?33 : 34;
    const int tc2 = ss==0?24: ss==1?27: ss==2?28 : ss==3?31 : ss==4?32 : 35;

    const float mq  = __shfl(Mv, Q);
    const float mp  = __shfl(Mv, P);
    const float mc  = __shfl(Mv, C);
    const float mpc = __shfl(Mv, PC);

    float ra, rb, rd;
    {
        float sq, cq, sp, cp;
        __sincosf(0.5f*(mq + th[Q]), &sq, &cq);
        __sincosf(0.5f*(mp + th[P]), &sp, &cp);
        float aq = cp*cp*cq*cq + sp*sp*sq*sq;
        float bq = cq*sq;
        float dq = 1.0f - aq;

        float sc, cc, spc, cpc;
        __sincosf(0.5f*(mc + th[C]), &sc, &cc);
        __sincosf(0.5f*(mpc + th[PC]), &spc, &cpc);
        float ac = cpc*cpc*cc*cc + spc*spc*sc*sc;
        float bc = cc*sc;
        float dc = 1.0f - ac;

        float s2, c2;
        __sincosf(0.5f*th[tc2], &s2, &c2);
        float p0 = c2*c2*ac - 2.0f*c2*s2*bc + s2*s2*dc;

        float s1, c1;
        __sincosf(0.5f*th[tq2], &s1, &c1);
        ry_dm(aq, bq, dq, c1, s1);
        ra = p0*aq + (1.0f - p0)*dq;
        rb = bq;
        rd = p0*dq + (1.0f - p0)*aq;
    }

    // ---- Fold slot3(w13) into slot2(w10) ----
    {
        const float c38 = __shfl(gc, 2), s38 = __shfl(gs, 2);
        const float c39 = __shfl(gc, 3), s39 = __shfl(gs, 3);
        const float a3 = __shfl(ra, 3);
        const float b3 = __shfl(rb, 3);
        const float d3 = __shfl(rd, 3);
        float a = ra, b = rb, d = rd;
        ry_dm(a, b, d, c38, s38);          // post-RY b matters
        float p0 = c39*c39*a3 - 2.0f*c39*s39*b3 + s39*s39*d3;
        float fa = p0*a + (1.0f - p0)*d;
        float fd = p0*d + (1.0f - p0)*a;
        if (lig == 2) { ra = fa; rb = b; rd = fd; }   // lanes 2 and 34 (dup)
    }

    // ---- Eigendecomposition per lane ----
    float cph, sph, lam0;
    {
        float ad = ra - rd;
        float r  = sqrtf(ad*ad + 4.0f*rb*rb);
        lam0 = 0.5f * (1.0f + r);
        float c2p = (r > 1e-12f) ? ad / r : 1.0f;
        float s2p = (r > 1e-12f) ? 2.0f*rb / r : 0.0f;
        cph = sqrtf(fmaxf(0.0f, 0.5f*(1.0f + c2p)));
        sph = copysignf(sqrtf(fmaxf(0.0f, 0.5f*(1.0f - c2p))), s2p);
    }

    // ---- Broadcast per-DM-bit (cph, sph, lam0): chain slots {0,1,2,4,5} ----
    float u0[5], u1[5];
    float wgt = 1.0f;
    {
        const int slotOf[5] = {0, 1, 2, 4, 5};
#pragma unroll
        for (int b = 0; b < 5; ++b) {
            const float cb = __shfl(cph,  slotOf[b]);
            const float sb = __shfl(sph,  slotOf[b]);
            const float lb = __shfl(lam0, slotOf[b]);
            const int bit = (lig >> b) & 1;
            u0[b] = bit ? -sb : cb;
            u1[b] = bit ?  cb : sb;
            wgt  *= bit ? (1.0f - lb) : lb;
        }
    }

    // ---- Delayed-merge gate evolution (16 amps/lane, i4 = half) ----
    float c_, s_;
#define BC(id) do { c_ = __shfl(gc, (id)); s_ = __shfl(gs, (id)); } while (0)

    // Stage 1: ry36(b0), ry37(b1); merge with cx(0->1)
    BC(0); float v00 = c_*u0[0] - s_*u1[0], v01 = s_*u0[0] + c_*u1[0];
    BC(1); float v10 = c_*u0[1] - s_*u1[1], v11 = s_*u0[1] + c_*u1[1];
    float q01_0 = v00*v10, q01_1 = v01*v11, q01_2 = v00*v11, q01_3 = v01*v10;

    // Stage 3: ry42(b1) on q01; ry43(b2); merge with cx(1->2)
    BC(6);
    { float x = q01_0, y = q01_2; q01_0 = c_*x - s_*y; q01_2 = s_*x + c_*y;
      x = q01_1; y = q01_3;       q01_1 = c_*x - s_*y; q01_3 = s_*x + c_*y; }
    BC(7); float v20 = c_*u0[2] - s_*u1[2], v21 = s_*u0[2] + c_*u1[2];
    float q012[8];
    q012[0] = q01_0*v20; q012[1] = q01_1*v20; q012[2] = q01_2*v21; q012[3] = q01_3*v21;
    q012[4] = q01_0*v21; q012[5] = q01_1*v21; q012[6] = q01_2*v20; q012[7] = q01_3*v20;

    // ry44(b2) on q012
    BC(8);
#pragma unroll
    for (int j = 0; j < 4; ++j) {
        float x = q012[j], y = q012[j + 4];
        q012[j] = c_*x - s_*y; q012[j + 4] = s_*x + c_*y;
    }
    // ry46(b1) pre-merge (commutes with cx(2->3))
    BC(10);
    { float x, y;
      x = q012[0]; y = q012[2]; q012[0] = c_*x - s_*y; q012[2] = s_*x + c_*y;
      x = q012[1]; y = q012[3]; q012[1] = c_*x - s_*y; q012[3] = s_*x + c_*y;
      x = q012[4]; y = q012[6]; q012[4] = c_*x - s_*y; q012[6] = s_*x + c_*y;
      x = q012[5]; y = q012[7]; q012[5] = c_*x - s_*y; q012[7] = s_*x + c_*y; }
    // ry50(b0) MOVED pre-merge (commutes past cx(2->3), th47, cx(2->1),
    // th48, cx(3->4) — all disjoint from b0)
    BC(14);
    { float x, y;
      x = q012[0]; y = q012[1]; q012[0] = c_*x - s_*y; q012[1] = s_*x + c_*y;
      x = q012[2]; y = q012[3]; q012[2] = c_*x - s_*y; q012[3] = s_*x + c_*y;
      x = q012[4]; y = q012[5]; q012[4] = c_*x - s_*y; q012[5] = s_*x + c_*y;
      x = q012[6]; y = q012[7]; q012[6] = c_*x - s_*y; q012[7] = s_*x + c_*y; }

    // Stage 2: ry40(b3), ry41(b4); cx(4->3); this lane keeps i4 = half only.
    BC(4); float v30 = c_*u0[3] - s_*u1[3], v31 = s_*u0[3] + c_*u1[3];
    BC(5); float v4h = half ? (s_*u0[4] + c_*u1[4]) : (c_*u0[4] - s_*u1[4]);
    // q34 local[i3] = v3[i3 ^ half] * v4[half]
    float qA = (half ? v31 : v30) * v4h;     // i3 = 0
    float qB = (half ? v30 : v31) * v4h;     // i3 = 1
    // ry45(b3)
    BC(9);
    { float x = qA, y = qB; qA = c_*x - s_*y; qB = s_*x + c_*y; }
    // ry49(b4) pre-merge: cross-half mix
    BC(13);
    {
        const float oA = __shfl_xor(qA, 32);
        const float oB = __shfl_xor(qB, 32);
        const float sgn = half ? s_ : -s_;
        qA = c_*qA + sgn*oA;
        qB = c_*qB + sgn*oB;
    }

    // Merge with cx(2->3): amp16[j] = q012[j&7] * local[(j>>3 ^ j>>2)&1]
    float amp[16];
#pragma unroll
    for (int j = 0; j < 16; ++j) {
        const int sel = ((j >> 3) ^ (j >> 2)) & 1;
        amp[j] = q012[j & 7] * (sel ? qB : qA);
    }

    // Remaining gates at 16-amp width
    BC(11); apply_ry16<4>(amp, c_, s_);    // th47 b2
    // cx(2->1): bit2=1 -> flip bit1
    { float tmp;
      tmp = amp[4];  amp[4]  = amp[6];  amp[6]  = tmp;
      tmp = amp[5];  amp[5]  = amp[7];  amp[7]  = tmp;
      tmp = amp[12]; amp[12] = amp[14]; amp[14] = tmp;
      tmp = amp[13]; amp[13] = amp[15]; amp[15] = tmp; }
    BC(12); apply_ry16<8>(amp, c_, s_);    // th48 b3
    // cx(3->4): bit3=1 -> flip i4 (cross-half swap)
#pragma unroll
    for (int j = 8; j < 16; ++j) amp[j] = __shfl_xor(amp[j], 32);
    BC(15); apply_ry16<2>(amp, c_, s_);    // th51 b1
    // cx(1->0): bit1=1 -> flip bit0
    { float tmp;
      tmp = amp[2];  amp[2]  = amp[3];  amp[3]  = tmp;
      tmp = amp[6];  amp[6]  = amp[7];  amp[7]  = tmp;
      tmp = amp[10]; amp[10] = amp[11]; amp[11] = tmp;
      tmp = amp[14]; amp[14] = amp[15]; amp[15] = tmp; }

    // ---- Measurement with th52-56 folded: ev_b = cos*Z_b - sin*X_b ----
    float p[16];
#pragma unroll
    for (int j = 0; j < 16; ++j) p[j] = amp[j] * amp[j];

    float z0 = 0.f, z1 = 0.f, z2 = 0.f, z3, z4;
    float s0[8];
#pragma unroll
    for (int i = 0; i < 8; ++i) { s0[i] = p[2*i] + p[2*i+1]; z0 += p[2*i] - p[2*i+1]; }
    float s1v[4];
#pragma unroll
    for (int i = 0; i < 4; ++i) { s1v[i] = s0[2*i] + s0[2*i+1]; z1 += s0[2*i] - s0[2*i+1]; }
    float s2v[2];
#pragma unroll
    for (int i = 0; i < 2; ++i) { s2v[i] = s1v[2*i] + s1v[2*i+1]; z2 += s1v[2*i] - s1v[2*i+1]; }
    z3 = s2v[0] - s2v[1];
    const float tot = s2v[0] + s2v[1];
    z4 = half ? -tot : tot;
    const float zv[5] = {z0, z1, z2, z3, z4};

    // X_b (b=0..3): 2 * sum_{j: bit b=0} amp[j]*amp[j|m]  (per-half partial)
    float xv[5];
#pragma unroll
    for (int b = 0; b < 4; ++b) {
        const int m = 1 << b;
        float acc = 0.0f;
#pragma unroll
        for (int j = 0; j < 16; ++j)
            if (!(j & m)) acc += amp[j] * amp[j | m];
        xv[b] = 2.0f * acc;
    }
    // X4: cross-half inner product (wave-sum over both halves supplies the 2x)
    {
        float acc = 0.0f;
#pragma unroll
        for (int j = 0; j < 16; ++j) acc += amp[j] * __shfl_xor(amp[j], 32);
        xv[4] = acc;
    }

    // ev_b = wgt * ((c^2-s^2) Z_b - 2cs X_b), half-angle (c,s) of th[52+b]
    float ev[5];
#pragma unroll
    for (int b = 0; b < 5; ++b) {
        BC(16 + b);
        ev[b] = wgt * ((c_*c_ - s_*s_) * zv[b] - 2.0f*c_*s_ * xv[b]);
    }
#undef BC

#pragma unroll
    for (int off = 1; off < 64; off <<= 1) {
#pragma unroll
        for (int b = 0; b < 5; ++b) ev[b] += __shfl_xor(ev[b], off);
    }

    if (t < 5) {
        const float v = t==0 ? ev[0] : t==1 ? ev[1] : t==2 ? ev[2]
                      : t==3 ? ev[3] : ev[4];
        out[node*5 + t] = 3.14159265358979f * (1.0f - v);
    }
}

extern "C" void kernel_launch(void* const* d_in, const int* in_sizes, int n_in,
                              void* d_out, int out_size, void* d_ws, size_t ws_size,
                              hipStream_t stream) {
    const float* X  = (const float*)d_in[0];
    const float* e  = (const float*)d_in[1];
    const float* Ri = (const float*)d_in[2];
    const float* Ro = (const float*)d_in[3];
    const float* th = (const float*)d_in[4];
    float* out = (float*)d_out;

    nodenet_branch_kernel<<<4, 64, 0, stream>>>(X, e, Ri, Ro, th, out);
}